// Round 1
// baseline (238.081 us; speedup 1.0000x reference)
//
#include <hip/hip_runtime.h>
#include <math.h>

#define Bn 32
#define Cn 768
#define CRn 192
#define HWn 1024   // H*W = 32*32, contiguous innermost per (b,c)

// ---------------- Kernel 1: squeeze (mean over HW per (b,c)) ----------------
// One block per (b,c): 256 threads x float4 = 1024 floats, fully coalesced.
__global__ __launch_bounds__(256) void se_mean(const float* __restrict__ x,
                                               float* __restrict__ s) {
    const int bc = blockIdx.x;
    const float4* xp = (const float4*)(x + (size_t)bc * HWn);
    float4 v = xp[threadIdx.x];
    float sum = v.x + v.y + v.z + v.w;
    // wave64 shuffle reduction
    #pragma unroll
    for (int off = 32; off > 0; off >>= 1) sum += __shfl_down(sum, off);
    __shared__ float part[4];
    const int lane = threadIdx.x & 63;
    const int wid  = threadIdx.x >> 6;
    if (lane == 0) part[wid] = sum;
    __syncthreads();
    if (threadIdx.x == 0) {
        s[bc] = (part[0] + part[1] + part[2] + part[3]) * (1.0f / (float)HWn);
    }
}

// ---------------- Kernel 2: excitation MLP (per batch) ----------------------
// h = swish(s @ w1^T + b1); g = sigmoid(h @ w2^T + b2)
__global__ __launch_bounds__(256) void se_mlp(const float* __restrict__ s,
                                              const float* __restrict__ w1,
                                              const float* __restrict__ b1,
                                              const float* __restrict__ w2,
                                              const float* __restrict__ b2,
                                              float* __restrict__ g) {
    const int b = blockIdx.x;
    __shared__ __align__(16) float sl[Cn];
    __shared__ __align__(16) float hl[CRn];

    for (int i = threadIdx.x; i < Cn; i += 256) sl[i] = s[b * Cn + i];
    __syncthreads();

    if (threadIdx.x < CRn) {
        const int j = threadIdx.x;
        const float4* wr = (const float4*)(w1 + (size_t)j * Cn); // w1 row contiguous
        const float4* sp = (const float4*)sl;
        float acc = 0.0f;
        #pragma unroll 4
        for (int k = 0; k < Cn / 4; ++k) {
            float4 wv = wr[k];
            float4 sv = sp[k];
            acc += wv.x * sv.x + wv.y * sv.y + wv.z * sv.z + wv.w * sv.w;
        }
        acc += b1[j];
        hl[j] = acc / (1.0f + expf(-acc)); // swish = x * sigmoid(x)
    }
    __syncthreads();

    for (int j = threadIdx.x; j < Cn; j += 256) {
        const float4* wr = (const float4*)(w2 + (size_t)j * CRn); // w2 row contiguous
        const float4* hp = (const float4*)hl;
        float acc = 0.0f;
        #pragma unroll 4
        for (int k = 0; k < CRn / 4; ++k) {
            float4 wv = wr[k];
            float4 hv = hp[k];
            acc += wv.x * hv.x + wv.y * hv.y + wv.z * hv.z + wv.w * hv.w;
        }
        acc += b2[j];
        g[b * Cn + j] = 1.0f / (1.0f + expf(-acc));
    }
}

// ---------------- Kernel 3: scale (broadcast multiply) ----------------------
// One block per (b,c); g[blockIdx.x] is block-uniform -> scalar load.
__global__ __launch_bounds__(256) void se_scale(const float* __restrict__ x,
                                                const float* __restrict__ g,
                                                float* __restrict__ out) {
    const int bc = blockIdx.x;
    const float gv = g[bc];
    const float4* xp = (const float4*)(x + (size_t)bc * HWn);
    float4* op = (float4*)(out + (size_t)bc * HWn);
    float4 v = xp[threadIdx.x];
    v.x *= gv; v.y *= gv; v.z *= gv; v.w *= gv;
    op[threadIdx.x] = v;
}

extern "C" void kernel_launch(void* const* d_in, const int* in_sizes, int n_in,
                              void* d_out, int out_size, void* d_ws, size_t ws_size,
                              hipStream_t stream) {
    const float* x  = (const float*)d_in[0];
    const float* w1 = (const float*)d_in[1];
    const float* b1 = (const float*)d_in[2];
    const float* w2 = (const float*)d_in[3];
    const float* b2 = (const float*)d_in[4];
    float* out = (float*)d_out;

    float* s = (float*)d_ws;            // [B*C] means
    float* g = s + (size_t)Bn * Cn;     // [B*C] gates

    se_mean <<<Bn * Cn, 256, 0, stream>>>(x, s);
    se_mlp  <<<Bn,      256, 0, stream>>>(s, w1, b1, w2, b2, g);
    se_scale<<<Bn * Cn, 256, 0, stream>>>(x, g, out);
}

// Round 2
// 195.388 us; speedup vs baseline: 1.2185x; 1.2185x over previous
//
#include <hip/hip_runtime.h>
#include <math.h>

#define Bn 32
#define Cn 768
#define CRn 192
#define HWn 1024   // H*W = 32*32, contiguous innermost per (b,c)

// ---------------- Kernel 1: squeeze (mean over HW per (b,c)) ----------------
// One block per (b,c): 256 threads x float4 = 1024 floats, fully coalesced.
__global__ __launch_bounds__(256) void se_mean(const float* __restrict__ x,
                                               float* __restrict__ s) {
    const int bc = blockIdx.x;
    const float4* xp = (const float4*)(x + (size_t)bc * HWn);
    float4 v = xp[threadIdx.x];
    float sum = v.x + v.y + v.z + v.w;
    #pragma unroll
    for (int off = 32; off > 0; off >>= 1) sum += __shfl_down(sum, off);
    __shared__ float part[4];
    const int lane = threadIdx.x & 63;
    const int wid  = threadIdx.x >> 6;
    if (lane == 0) part[wid] = sum;
    __syncthreads();
    if (threadIdx.x == 0) {
        s[bc] = (part[0] + part[1] + part[2] + part[3]) * (1.0f / (float)HWn);
    }
}

// ---------------- Kernel 2: h = swish(s @ w1^T + b1) ------------------------
// One WAVE per (b,j) dot of length 768: lane does 3 coalesced float4 loads
// from the w1 row and from s[b,:], then wave-reduce. Grid covers all CUs.
__global__ __launch_bounds__(256) void se_h(const float* __restrict__ s,
                                            const float* __restrict__ w1,
                                            const float* __restrict__ b1,
                                            float* __restrict__ h) {
    const int wid  = threadIdx.x >> 6;
    const int lane = threadIdx.x & 63;
    const int b = blockIdx.x / (CRn / 4);           // 4 dots per block (one per wave)
    const int j = (blockIdx.x % (CRn / 4)) * 4 + wid;

    const float4* wr = (const float4*)(w1 + (size_t)j * Cn);   // 192 float4s
    const float4* sp = (const float4*)(s + (size_t)b * Cn);
    float acc = 0.0f;
    #pragma unroll
    for (int t = 0; t < 3; ++t) {
        float4 wv = wr[lane + 64 * t];
        float4 sv = sp[lane + 64 * t];
        acc += wv.x * sv.x + wv.y * sv.y + wv.z * sv.z + wv.w * sv.w;
    }
    #pragma unroll
    for (int off = 32; off > 0; off >>= 1) acc += __shfl_down(acc, off);
    if (lane == 0) {
        float v = acc + b1[j];
        h[b * CRn + j] = v / (1.0f + expf(-v));     // swish
    }
}

// ---------------- Kernel 3: fused gate + scale ------------------------------
// One block per (b,c). Wave 0 computes g = sigmoid(h[b,:] . w2[c,:] + b2[c])
// (192-long dot, 3 elems/lane) while every thread's x float4 load is already
// in flight; then all 256 threads scale and store.
__global__ __launch_bounds__(256) void se_scale_g(const float* __restrict__ x,
                                                  const float* __restrict__ h,
                                                  const float* __restrict__ w2,
                                                  const float* __restrict__ b2,
                                                  float* __restrict__ out) {
    const int bc = blockIdx.x;
    const int b = bc / Cn;
    const int c = bc % Cn;

    const float4* xp = (const float4*)(x + (size_t)bc * HWn);
    float4* op = (float4*)(out + (size_t)bc * HWn);
    float4 v = xp[threadIdx.x];          // issue the streaming load early

    __shared__ float gs;
    if (threadIdx.x < 64) {
        const int lane = threadIdx.x;
        const float* hp = h  + (size_t)b * CRn;
        const float* wp = w2 + (size_t)c * CRn;
        float acc = 0.0f;
        #pragma unroll
        for (int t = 0; t < 3; ++t) {
            acc += hp[lane + 64 * t] * wp[lane + 64 * t];
        }
        #pragma unroll
        for (int off = 32; off > 0; off >>= 1) acc += __shfl_down(acc, off);
        if (lane == 0) {
            float z = acc + b2[c];
            gs = 1.0f / (1.0f + expf(-z));
        }
    }
    __syncthreads();
    const float gv = gs;
    v.x *= gv; v.y *= gv; v.z *= gv; v.w *= gv;
    op[threadIdx.x] = v;
}

extern "C" void kernel_launch(void* const* d_in, const int* in_sizes, int n_in,
                              void* d_out, int out_size, void* d_ws, size_t ws_size,
                              hipStream_t stream) {
    const float* x  = (const float*)d_in[0];
    const float* w1 = (const float*)d_in[1];
    const float* b1 = (const float*)d_in[2];
    const float* w2 = (const float*)d_in[3];
    const float* b2 = (const float*)d_in[4];
    float* out = (float*)d_out;

    float* s = (float*)d_ws;            // [B*C]  means
    float* h = s + (size_t)Bn * Cn;     // [B*Cr] hidden activations

    se_mean   <<<Bn * Cn,        256, 0, stream>>>(x, s);
    se_h      <<<Bn * (CRn / 4), 256, 0, stream>>>(s, w1, b1, h);
    se_scale_g<<<Bn * Cn,        256, 0, stream>>>(x, h, w2, b2, out);
}